// Round 1
// baseline (181.894 us; speedup 1.0000x reference)
//
#include <hip/hip_runtime.h>
#include <cstdint>

typedef __attribute__((ext_vector_type(8))) short bf16x8;   // 8 bf16 = 4 VGPRs
typedef __attribute__((ext_vector_type(4))) float f32x4;    // MFMA C/D
typedef __attribute__((ext_vector_type(4))) float f4;
typedef __attribute__((ext_vector_type(4))) unsigned short u16x4;
typedef unsigned short u16;

__device__ __forceinline__ u16 f2bf(float f) {
  uint32_t u = __builtin_bit_cast(uint32_t, f);
  u += 0x7fffu + ((u >> 16) & 1u);          // round-to-nearest-even
  return (u16)(u >> 16);
}

__device__ __forceinline__ void async_cp16(const void* g, void* l) {
  __builtin_amdgcn_global_load_lds(
      (const __attribute__((address_space(1))) uint32_t*)g,
      (__attribute__((address_space(3))) uint32_t*)l, 16, 0, 0);
}

__global__ __launch_bounds__(256) void cast_f32_bf16(
    const float* __restrict__ src, u16* __restrict__ dst, int n) {
  int i = (blockIdx.x * 256 + threadIdx.x) * 4;
  if (i < n) {
    f4 v = *(const f4*)(src + i);
    u16x4 o;
    o.x = f2bf(v.x); o.y = f2bf(v.y); o.z = f2bf(v.z); o.w = f2bf(v.w);
    *(u16x4*)(dst + i) = o;
  }
}

// C = A (MxK) @ B^T (B is NxK), bf16 inputs, fp32 accumulate.
// EPI=0: store fp32 to Cout[M x N]
// EPI=1: xf-transform  -> Cbf[M x 2N]: [f]=xf*relu(xf), [N+f]=1-relu(xf)
// EPI=2: pf-transform  -> Cbf[M x 2N]: [f]=th*c-al*(1-pres), [N+f]=-be*c
template<int TM, int TN, int EPI>
__global__ __launch_bounds__(256) void gemm_bt(
    const u16* __restrict__ A, const u16* __restrict__ B,
    float* __restrict__ Cout, u16* __restrict__ Cbf,
    int M, int N, int K,
    const float* __restrict__ alpha, const float* __restrict__ beta,
    const float* __restrict__ theta) {
  constexpr int BK = 64;                 // k-tile (elements)
  constexpr int WM = TM / 2, WN = TN / 2;
  constexpr int MT = WM / 16, NT = WN / 16;
  __shared__ u16 lds[(TM + TN) * BK];    // A tile then B tile, 16B-chunk XOR-swizzled

  const int tid  = threadIdx.x;
  const int lane = tid & 63;
  const int wave = tid >> 6;
  const int wrow = wave >> 1, wcol = wave & 1;
  const int bm = blockIdx.x * TM;
  const int bn = blockIdx.y * TN;

  f32x4 acc[MT][NT] = {};

  for (int k0 = 0; k0 < K; k0 += BK) {
    // ---- stage A tile: TM rows x 64 cols, 16B chunks, XOR-swizzled within row ----
    #pragma unroll
    for (int it = 0; it < TM / 32; ++it) {
      int c = it * 256 + tid;            // chunk index = LDS position
      int row = c >> 3, pc = c & 7;
      int gc = pc ^ (row & 7);           // which global 16B chunk lands here
      const u16* g = A + (size_t)(bm + row) * K + (k0 + gc * 8);
      async_cp16(g, &lds[(it * 256 + wave * 64) * 8]);   // wave-uniform base + lane*16
    }
    // ---- stage B tile ----
    #pragma unroll
    for (int it = 0; it < TN / 32; ++it) {
      int c = it * 256 + tid;
      int row = c >> 3, pc = c & 7;
      int gc = pc ^ (row & 7);
      const u16* g = B + (size_t)(bn + row) * K + (k0 + gc * 8);
      async_cp16(g, &lds[TM * BK + (it * 256 + wave * 64) * 8]);
    }
    __syncthreads();

    // ---- 2 k-steps of 16x16x32 MFMA ----
    #pragma unroll
    for (int s = 0; s < 2; ++s) {
      const int h = s * 4 + (lane >> 4); // which 16B chunk along K this lane needs
      bf16x8 afr[MT], bfr[NT];
      #pragma unroll
      for (int i = 0; i < MT; ++i) {
        int r = wrow * WM + i * 16 + (lane & 15);
        afr[i] = *(const bf16x8*)&lds[(r * 8 + (h ^ (r & 7))) * 8];
      }
      #pragma unroll
      for (int j = 0; j < NT; ++j) {
        int r = wcol * WN + j * 16 + (lane & 15);
        bfr[j] = *(const bf16x8*)&lds[TM * BK + (r * 8 + (h ^ (r & 7))) * 8];
      }
      #pragma unroll
      for (int i = 0; i < MT; ++i)
        #pragma unroll
        for (int j = 0; j < NT; ++j)
          acc[i][j] = __builtin_amdgcn_mfma_f32_16x16x32_bf16(afr[i], bfr[j], acc[i][j], 0, 0, 0);
    }
    __syncthreads();
  }

  // ---- epilogue ----
  float th = 0.f, al = 0.f, be = 0.f;
  if constexpr (EPI == 2) { th = theta[0]; al = alpha[0]; be = beta[0]; }
  #pragma unroll
  for (int i = 0; i < MT; ++i) {
    const int gr0 = bm + wrow * WM + i * 16 + (lane >> 4) * 4;
    #pragma unroll
    for (int j = 0; j < NT; ++j) {
      const int gc = bn + wcol * WN + j * 16 + (lane & 15);
      #pragma unroll
      for (int r = 0; r < 4; ++r) {
        float v = acc[i][j][r];
        if constexpr (EPI == 0) {
          Cout[(size_t)(gr0 + r) * N + gc] = v;
        } else {
          float pres = v > 0.f ? v : 0.f;
          float o1, o2;
          if constexpr (EPI == 1) { o1 = v * pres; o2 = 1.f - pres; }
          else { float cc = v * pres; o1 = th * cc - al * (1.f - pres); o2 = -be * cc; }
          size_t base = (size_t)(gr0 + r) * (size_t)(2 * N) + gc;
          Cbf[base]     = f2bf(o1);
          Cbf[base + N] = f2bf(o2);
        }
      }
    }
  }
}

extern "C" void kernel_launch(void* const* d_in, const int* in_sizes, int n_in,
                              void* d_out, int out_size, void* d_ws, size_t ws_size,
                              hipStream_t stream) {
  const float* x     = (const float*)d_in[0];
  const float* feat  = (const float*)d_in[1];
  const float* proto = (const float*)d_in[2];
  const float* alpha = (const float*)d_in[3];
  const float* beta  = (const float*)d_in[4];
  const float* theta = (const float*)d_in[5];
  float* out = (float*)d_out;

  constexpr int Bb = 4096, Ii = 1024, Pp = 512, Ff = 2048;

  char* ws = (char*)d_ws;
  size_t off = 0;
  u16* xb   = (u16*)(ws + off); off += (size_t)Bb * Ii * 2;      // 8.4 MB
  u16* fb   = (u16*)(ws + off); off += (size_t)Ff * Ii * 2;      // 4.2 MB
  u16* pb   = (u16*)(ws + off); off += (size_t)Pp * Ii * 2;      // 1.0 MB
  u16* Acat = (u16*)(ws + off); off += (size_t)Bb * 2 * Ff * 2;  // 33.6 MB
  u16* Bcat = (u16*)(ws + off);                                   // 4.2 MB  (total ~51.4 MB)

  // fp32 -> bf16 casts
  cast_f32_bf16<<<(Bb * Ii / 4 + 255) / 256, 256, 0, stream>>>(x, xb, Bb * Ii);
  cast_f32_bf16<<<(Ff * Ii / 4 + 255) / 256, 256, 0, stream>>>(feat, fb, Ff * Ii);
  cast_f32_bf16<<<(Pp * Ii / 4 + 255) / 256, 256, 0, stream>>>(proto, pb, Pp * Ii);

  // GEMM1: pf = proto @ feat^T (512 x 2048, K=1024) -> Bcat (scalars folded)
  gemm_bt<64, 64, 2><<<dim3(Pp / 64, Ff / 64), 256, 0, stream>>>(
      pb, fb, nullptr, Bcat, Pp, Ff, Ii, alpha, beta, theta);

  // GEMM2: xf = x @ feat^T (4096 x 2048, K=1024) -> Acat
  gemm_bt<128, 128, 1><<<dim3(Bb / 128, Ff / 128), 256, 0, stream>>>(
      xb, fb, nullptr, Acat, Bb, Ff, Ii, nullptr, nullptr, nullptr);

  // GEMM3: out = Acat @ Bcat^T (4096 x 512, K=4096) fp32 out
  gemm_bt<128, 64, 0><<<dim3(Bb / 128, Pp / 64), 256, 0, stream>>>(
      Acat, Bcat, out, nullptr, Bb, Pp, 2 * Ff, nullptr, nullptr, nullptr);
}

// Round 2
// 165.006 us; speedup vs baseline: 1.1023x; 1.1023x over previous
//
#include <hip/hip_runtime.h>
#include <cstdint>

typedef __attribute__((ext_vector_type(8))) short bf16x8;   // 8 bf16 = 4 VGPRs
typedef __attribute__((ext_vector_type(4))) float f32x4;    // MFMA C/D
typedef __attribute__((ext_vector_type(4))) float f4;
typedef __attribute__((ext_vector_type(4))) unsigned short u16x4;
typedef unsigned short u16;

__device__ __forceinline__ u16 f2bf(float f) {
  uint32_t u = __builtin_bit_cast(uint32_t, f);
  u += 0x7fffu + ((u >> 16) & 1u);          // round-to-nearest-even
  return (u16)(u >> 16);
}

__device__ __forceinline__ void async_cp16(const void* g, void* l) {
  __builtin_amdgcn_global_load_lds(
      (const __attribute__((address_space(1))) uint32_t*)g,
      (__attribute__((address_space(3))) uint32_t*)l, 16, 0, 0);
}

// One fused cast for x | features | prototypes -> contiguous bf16 region in ws
__global__ __launch_bounds__(256) void cast3(
    const float* __restrict__ x, const float* __restrict__ f,
    const float* __restrict__ p, u16* __restrict__ dst,
    int n1, int n2, int n3) {
  int i = (blockIdx.x * 256 + threadIdx.x) * 4;
  const float* src;
  int local;
  if (i < n1) { src = x; local = i; }
  else if (i < n1 + n2) { src = f; local = i - n1; }
  else if (i < n1 + n2 + n3) { src = p; local = i - n1 - n2; }
  else return;
  f4 v = *(const f4*)(src + local);
  u16x4 o;
  o.x = f2bf(v.x); o.y = f2bf(v.y); o.z = f2bf(v.z); o.w = f2bf(v.w);
  *(u16x4*)(dst + i) = o;
}

__global__ __launch_bounds__(256) void zero_f32(float* __restrict__ p, int n4) {
  int i = blockIdx.x * 256 + threadIdx.x;
  if (i < n4) ((f4*)p)[i] = (f4){0.f, 0.f, 0.f, 0.f};
}

// ---- shared main loop: C += A(tile, MxK-rowmajor) @ B(tile, NxK-rowmajor)^T ----
// A,B pre-offset to the tile base row. 16B-chunk XOR swizzle (verified 0 bank conflicts).
template<int TM, int TN>
__device__ __forceinline__ void mainloop(
    const u16* __restrict__ A, const u16* __restrict__ B, int K,
    int kbeg, int kend, int tid, u16* lds, f32x4 (&acc)[TM / 32][TN / 32]) {
  constexpr int BK = 64;
  constexpr int WM = TM / 2, WN = TN / 2;
  constexpr int MT = TM / 32, NT = TN / 32;
  const int lane = tid & 63;
  const int wave = tid >> 6;
  const int wrow = wave >> 1, wcol = wave & 1;

  for (int k0 = kbeg; k0 < kend; k0 += BK) {
    #pragma unroll
    for (int it = 0; it < TM / 32; ++it) {
      int c = it * 256 + tid;            // chunk index = LDS position
      int row = c >> 3, pc = c & 7;
      int gc = pc ^ (row & 7);           // which global 16B chunk lands here
      async_cp16(A + (size_t)row * K + (k0 + gc * 8),
                 &lds[(it * 256 + wave * 64) * 8]);
    }
    #pragma unroll
    for (int it = 0; it < TN / 32; ++it) {
      int c = it * 256 + tid;
      int row = c >> 3, pc = c & 7;
      int gc = pc ^ (row & 7);
      async_cp16(B + (size_t)row * K + (k0 + gc * 8),
                 &lds[TM * BK + (it * 256 + wave * 64) * 8]);
    }
    __syncthreads();

    #pragma unroll
    for (int s = 0; s < 2; ++s) {
      const int h = s * 4 + (lane >> 4);
      bf16x8 afr[MT], bfr[NT];
      #pragma unroll
      for (int i = 0; i < MT; ++i) {
        int r = wrow * WM + i * 16 + (lane & 15);
        afr[i] = *(const bf16x8*)&lds[(r * 8 + (h ^ (r & 7))) * 8];
      }
      #pragma unroll
      for (int j = 0; j < NT; ++j) {
        int r = wcol * WN + j * 16 + (lane & 15);
        bfr[j] = *(const bf16x8*)&lds[TM * BK + (r * 8 + (h ^ (r & 7))) * 8];
      }
      #pragma unroll
      for (int i = 0; i < MT; ++i)
        #pragma unroll
        for (int j = 0; j < NT; ++j)
          acc[i][j] = __builtin_amdgcn_mfma_f32_16x16x32_bf16(afr[i], bfr[j], acc[i][j], 0, 0, 0);
    }
    __syncthreads();
  }
}

// ---- GEMM1+GEMM2 merged: [x; proto](4608 x 1024) @ feat^T, per-block epilogue ----
// x-rows  -> Acat[row, f]=xf*relu(xf), Acat[row, 2048+f]=1-relu(xf)
// p-rows  -> Bcat[row, f]=th*c-al*(1-pres), Bcat[row, 2048+f]=-be*c
__global__ __launch_bounds__(256) void gemm12(
    const u16* __restrict__ xb, const u16* __restrict__ pb,
    const u16* __restrict__ fb, u16* __restrict__ Acat, u16* __restrict__ Bcat,
    const float* __restrict__ alpha, const float* __restrict__ beta,
    const float* __restrict__ theta) {
  constexpr int TM = 128, TN = 64, K = 1024, N = 2048;
  constexpr int WM = TM / 2, WN = TN / 2;
  constexpr int MT = TM / 32, NT = TN / 32;
  __shared__ u16 lds[(TM + TN) * 64];

  const int tid = threadIdx.x;
  const int lane = tid & 63;
  const int wave = tid >> 6;
  const int wrow = wave >> 1, wcol = wave & 1;
  const int bm_all = blockIdx.x * TM;
  const int bn = blockIdx.y * TN;
  const bool is_x = bm_all < 4096;
  const u16* A = is_x ? xb + (size_t)bm_all * K : pb + (size_t)(bm_all - 4096) * K;
  const u16* B = fb + (size_t)bn * K;

  f32x4 acc[MT][NT] = {};
  mainloop<TM, TN>(A, B, K, 0, K, tid, lds, acc);

  float th = 0.f, al = 0.f, be = 0.f;
  if (!is_x) { th = theta[0]; al = alpha[0]; be = beta[0]; }
  u16* dst = is_x ? Acat : Bcat;
  const int rbase = is_x ? bm_all : bm_all - 4096;

  #pragma unroll
  for (int i = 0; i < MT; ++i) {
    const int gr0 = rbase + wrow * WM + i * 16 + (lane >> 4) * 4;
    #pragma unroll
    for (int j = 0; j < NT; ++j) {
      const int gc = bn + wcol * WN + j * 16 + (lane & 15);
      #pragma unroll
      for (int r = 0; r < 4; ++r) {
        float v = acc[i][j][r];
        float pres = v > 0.f ? v : 0.f;
        float o1, o2;
        if (is_x) { o1 = v * pres; o2 = 1.f - pres; }
        else { float cc = v * pres; o1 = th * cc - al * (1.f - pres); o2 = -be * cc; }
        size_t base = (size_t)(gr0 + r) * (size_t)(2 * N) + gc;
        dst[base]     = f2bf(o1);
        dst[base + N] = f2bf(o2);
      }
    }
  }
}

// ---- GEMM3 split-K: out(4096x512) += Acat @ Bcat^T over K=4096, 4 splits ----
__global__ __launch_bounds__(256) void gemm3(
    const u16* __restrict__ Acat, const u16* __restrict__ Bcat,
    float* __restrict__ out) {
  constexpr int TM = 128, TN = 64, K = 4096, N = 512, KSPLIT = 4;
  constexpr int WM = TM / 2, WN = TN / 2;
  constexpr int MT = TM / 32, NT = TN / 32;
  __shared__ u16 lds[(TM + TN) * 64];

  const int tid = threadIdx.x;
  const int lane = tid & 63;
  const int wave = tid >> 6;
  const int wrow = wave >> 1, wcol = wave & 1;
  const int bm = blockIdx.x * TM;
  const int bn = blockIdx.y * TN;
  const int kbeg = blockIdx.z * (K / KSPLIT);
  const int kend = kbeg + (K / KSPLIT);

  f32x4 acc[MT][NT] = {};
  mainloop<TM, TN>(Acat + (size_t)bm * K, Bcat + (size_t)bn * K, K, kbeg, kend,
                   tid, lds, acc);

  #pragma unroll
  for (int i = 0; i < MT; ++i) {
    const int gr0 = bm + wrow * WM + i * 16 + (lane >> 4) * 4;
    #pragma unroll
    for (int j = 0; j < NT; ++j) {
      const int gc = bn + wcol * WN + j * 16 + (lane & 15);
      #pragma unroll
      for (int r = 0; r < 4; ++r)
        unsafeAtomicAdd(&out[(size_t)(gr0 + r) * N + gc], acc[i][j][r]);
    }
  }
}

extern "C" void kernel_launch(void* const* d_in, const int* in_sizes, int n_in,
                              void* d_out, int out_size, void* d_ws, size_t ws_size,
                              hipStream_t stream) {
  const float* x     = (const float*)d_in[0];
  const float* feat  = (const float*)d_in[1];
  const float* proto = (const float*)d_in[2];
  const float* alpha = (const float*)d_in[3];
  const float* beta  = (const float*)d_in[4];
  const float* theta = (const float*)d_in[5];
  float* out = (float*)d_out;

  constexpr int Bb = 4096, Ii = 1024, Pp = 512, Ff = 2048;

  char* ws = (char*)d_ws;
  size_t off = 0;
  u16* xb   = (u16*)(ws + off); off += (size_t)Bb * Ii * 2;      // 8.4 MB
  u16* fb   = (u16*)(ws + off); off += (size_t)Ff * Ii * 2;      // 4.2 MB
  u16* pb   = (u16*)(ws + off); off += (size_t)Pp * Ii * 2;      // 1.0 MB
  u16* Acat = (u16*)(ws + off); off += (size_t)Bb * 2 * Ff * 2;  // 33.6 MB
  u16* Bcat = (u16*)(ws + off);                                   // 4.2 MB (total ~51.4 MB)

  const int n1 = Bb * Ii, n2 = Ff * Ii, n3 = Pp * Ii;
  cast3<<<((n1 + n2 + n3) / 4 + 255) / 256, 256, 0, stream>>>(
      x, feat, proto, xb, n1, n2, n3);

  zero_f32<<<(Bb * Pp / 4 + 255) / 256, 256, 0, stream>>>(out, Bb * Pp / 4);

  // merged GEMM1+GEMM2: M=4608 (36 row-tiles of 128), N=2048 (32 col-tiles of 64)
  gemm12<<<dim3(36, 32), 256, 0, stream>>>(xb, pb, fb, Acat, Bcat, alpha, beta, theta);

  // GEMM3: 4096x512, K=4096 split 4 ways -> 1024 blocks, atomic accumulate
  gemm3<<<dim3(Bb / 128, Pp / 64, 4), 256, 0, stream>>>(Acat, Bcat, out);
}